// Round 13
// baseline (120.182 us; speedup 1.0000x reference)
//
#include <hip/hip_runtime.h>

typedef _Float16 half_t;
typedef __fp16   fp16x2 __attribute__((ext_vector_type(2)));
typedef _Float16 half4_t __attribute__((ext_vector_type(4)));
typedef _Float16 half8   __attribute__((ext_vector_type(8)));
typedef float    f32x4   __attribute__((ext_vector_type(4)));
typedef unsigned short u16x8 __attribute__((ext_vector_type(8)));

#define KP_S    0.057735026918962574f  // 0.1/sqrt(3)
#define INV_EXT 11.547005383792515f    // 1/(0.05*sqrt(3))
#define GPITCH  3616                   // G bytes/query: 64*28*2 data + 32 pad
#define NBLK    512                    // persistent blocks = 2/CU exactly
#define NTILE   2500                   // 40000 queries / 16 per tile
#define WT_BYTES (64 * 1792 * 2)       // 229376
#define XH_BYTES (40000 * 64 * 2)      // 5120000
#define PH_BYTES (40000 * 4 * 2)       // 320000 (half4 per point)

union H8 { half8 v; fp16x2 h2[4]; };
union H4 { half4_t v; fp16x2 h2[2]; };

// WT[o][k], k = i*28 + l (fp16); l==27 zero pad mirrors G's pitch-28 layout.
// Channel permutation c = 4*(i&15) + (i>>4): MFMA column (nt,lr) holds x-channel
// 4*lr+nt so the phase-C gather is one 8B fp16 load per lane per row.
__global__ void build_wt(const float* __restrict__ W, half_t* __restrict__ WT) {
    int t = blockIdx.x * 256 + threadIdx.x;       // 64*1792 = 114688 exact
    if (t >= 64 * 1792) return;
    int o = t / 1792, k = t - o * 1792;
    int i = k / 28,   l = k - i * 28;
    int c = 4 * (i & 15) + (i >> 4);              // permuted channel index
    WT[t] = (l < 27) ? (half_t)W[(l * 64 + c) * 64 + o] : (half_t)0.f;
}

// x (f32, [40000][64]) -> xh (fp16, same layout): 128 B/row = 1 cache line
__global__ void build_xh(const float* __restrict__ x, half_t* __restrict__ xh) {
    int t = blockIdx.x * 256 + threadIdx.x;       // 2500*256 = 640000 exact
    f32x4 v = *(const f32x4*)(x + t * 4);
    H4 h;
    h.h2[0] = __builtin_amdgcn_cvt_pkrtz(v.x, v.y);
    h.h2[1] = __builtin_amdgcn_cvt_pkrtz(v.z, v.w);
    *(half4_t*)(xh + t * 4) = h.v;
}

// q_pts/s_pts (f32 [40000][3]) -> qh/sh (fp16 half4 {x,y,z,0}): one 8B load/pt
__global__ void build_ph(const float* __restrict__ q_pts, const float* __restrict__ s_pts,
                         half_t* __restrict__ qh, half_t* __restrict__ sh) {
    int i = blockIdx.x * 256 + threadIdx.x;
    if (i >= 40000) return;
    H4 a, b;
    a.h2[0] = __builtin_amdgcn_cvt_pkrtz(q_pts[3*i], q_pts[3*i+1]);
    a.h2[1] = __builtin_amdgcn_cvt_pkrtz(q_pts[3*i+2], 0.f);
    b.h2[0] = __builtin_amdgcn_cvt_pkrtz(s_pts[3*i], s_pts[3*i+1]);
    b.h2[1] = __builtin_amdgcn_cvt_pkrtz(s_pts[3*i+2], 0.f);
    *(half4_t*)(qh + 4*i) = a.v;
    *(half4_t*)(sh + 4*i) = b.v;
}

// issue one query's x-gather into 8 half4 regs (16 VGPR)
#define ISSUE_XV1(BUF, Q, XV) do {                                             \
    u16x8 id8 = *(const u16x8*)&idx_lds[BUF][Q][8 * g];                        \
    _Pragma("unroll")                                                          \
    for (int j = 0; j < 8; ++j) {                                              \
        if constexpr (XHALF) {                                                 \
            XV[j] = *(const half4_t*)(xh + (int)id8[j] * 64 + 4 * lr);         \
        } else {                                                               \
            f32x4 t4 = *(const f32x4*)(x + (int)id8[j] * 64 + 4 * lr);         \
            H4 hh;                                                             \
            hh.h2[0] = __builtin_amdgcn_cvt_pkrtz(t4.x, t4.y);                 \
            hh.h2[1] = __builtin_amdgcn_cvt_pkrtz(t4.z, t4.w);                 \
            XV[j] = hh.v;                                                      \
        }                                                                      \
    }                                                                          \
} while (0)

// transpose 8 half4 -> 4 half8 B-fragments (pure fp16 lane-local moves)
#define PACK_B(XV, BF) do {                                                    \
    _Pragma("unroll")                                                          \
    for (int nt = 0; nt < 4; ++nt) {                                           \
        half8 b;                                                               \
        _Pragma("unroll")                                                      \
        for (int j = 0; j < 8; ++j) b[j] = XV[j][nt];                          \
        BF[nt].v = b;                                                          \
    }                                                                          \
} while (0)

// per-lane influence weights (fp16 nbr, paired b128 reads) + stage-1 MFMAs + G dump
#define MFMA_DUMP(Q, CUR, BF) do {                                             \
    float w0v[8], w1v[8];                                                      \
    _Pragma("unroll")                                                          \
    for (int j2 = 0; j2 < 4; ++j2) {                                           \
        half8 nb2 = *(const half8*)&nbr_lds[CUR][Q][8 * g + 2 * j2];           \
        _Pragma("unroll")                                                      \
        for (int u = 0; u < 2; ++u) {                                          \
            const int j = 2 * j2 + u;                                          \
            float nx = (float)nb2[4*u+0], ny = (float)nb2[4*u+1], nz = (float)nb2[4*u+2]; \
            float dx = nx - kx0, dy = ny - ky0, dz = nz - kz0;                 \
            w0v[j] = fmaxf(fmaf(__builtin_amdgcn_sqrtf(dx*dx + dy*dy + dz*dz), -INV_EXT, 1.f), 0.f); \
            float ex = nx - kx1, ey = ny - ky1, ez = nz - kz1;                 \
            w1v[j] = fmaxf(fmaf(__builtin_amdgcn_sqrtf(ex*ex + ey*ey + ez*ez), -INV_EXT, cbias), 0.f); \
        }                                                                      \
    }                                                                          \
    H8 A0, A1;                                                                 \
    _Pragma("unroll")                                                          \
    for (int p = 0; p < 4; ++p) {                                              \
        A0.h2[p] = __builtin_amdgcn_cvt_pkrtz(w0v[2*p], w0v[2*p+1]);           \
        A1.h2[p] = __builtin_amdgcn_cvt_pkrtz(w1v[2*p], w1v[2*p+1]);           \
    }                                                                          \
    char* gq = g_mem + (Q) * GPITCH;                                           \
    _Pragma("unroll")                                                          \
    for (int nt = 0; nt < 4; ++nt) {                                           \
        f32x4 z = {0.f, 0.f, 0.f, 0.f};                                        \
        f32x4 c0 = __builtin_amdgcn_mfma_f32_16x16x32_f16(A0.v, BF[nt].v, z, 0, 0, 0); \
        f32x4 c1 = __builtin_amdgcn_mfma_f32_16x16x32_f16(A1.v, BF[nt].v, z, 0, 0, 0); \
        const int ic = 16 * nt + lr;                                           \
        H4 h0;                                                                 \
        h0.h2[0] = __builtin_amdgcn_cvt_pkrtz(c0[0], c0[1]);                   \
        h0.h2[1] = __builtin_amdgcn_cvt_pkrtz(c0[2], c0[3]);                   \
        *(half4_t*)(gq + 2 * (ic * 28 + 4 * g)) = h0.v;                        \
        if (4 * g < 12) {                                                      \
            H4 h1;                                                             \
            h1.h2[0] = __builtin_amdgcn_cvt_pkrtz(c1[0], c1[1]);               \
            h1.h2[1] = __builtin_amdgcn_cvt_pkrtz(c1[2], c1[3]);               \
            *(half4_t*)(gq + 2 * (ic * 28 + 16 + 4 * g)) = h1.v;               \
        }                                                                      \
    }                                                                          \
} while (0)

#define BODY(T, TNN, CUR, XV) do {                                             \
    /* issue qB gather first (8 loads in flight across qA compute) */          \
    half4_t xvB[8];                                                            \
    ISSUE_XV1(CUR, 2 * wid + 1, xvB);                                          \
    const int idxN = idxReg;                        /* 2-ahead: already here */ \
    idxReg = inds[((TNN) * 16 + aq) * 32 + ah];     /* prefetch for next iter */\
    H8 BFA[4];                                                                 \
    PACK_B(XV, BFA);                                                           \
    MFMA_DUMP(2 * wid, CUR, BFA);                                              \
    /* next-tile nbr: one 8B gather + one 8B sequential load, fp16 math */     \
    half4_t nv;                                                                \
    if constexpr (PH) {                                                        \
        half4_t sv = *(const half4_t*)(sh + 4 * idxN);                         \
        half4_t qv = *(const half4_t*)(qh + 4 * nnq);                          \
        nv = sv - qv;                                                          \
    } else {                                                                   \
        float dx = s_pts[idxN*3+0] - q_pts[nnq*3+0];                           \
        float dy = s_pts[idxN*3+1] - q_pts[nnq*3+1];                           \
        float dz = s_pts[idxN*3+2] - q_pts[nnq*3+2];                           \
        H4 t;                                                                  \
        t.h2[0] = __builtin_amdgcn_cvt_pkrtz(dx, dy);                          \
        t.h2[1] = __builtin_amdgcn_cvt_pkrtz(dz, 0.f);                         \
        nv = t.v;                                                              \
    }                                                                          \
    H8 BFB[4];                                                                 \
    PACK_B(xvB, BFB);                                                          \
    MFMA_DUMP(2 * wid + 1, CUR, BFB);                                          \
    idx_lds[(CUR) ^ 1][aq][ah] = (unsigned short)idxN;                         \
    nbr_lds[(CUR) ^ 1][aq][ah] = nv;                                           \
    __syncthreads();                                                           \
    /* refill XV with next tile's qA under phase D */                          \
    ISSUE_XV1((CUR) ^ 1, 2 * wid, XV);                                         \
    /* phase D: fx[16,64] = G @ WT^T; wave=(ot,kh); steps 0..6 from wreg */    \
    f32x4 accA = {0.f, 0.f, 0.f, 0.f}, accB = {0.f, 0.f, 0.f, 0.f};            \
    _Pragma("unroll")                                                          \
    for (int s = 0; s < 7; ++s) {                                              \
        half8 a = *(const half8*)(gb + 64 * s + 16 * g);                       \
        accA = __builtin_amdgcn_mfma_f32_16x16x32_f16(a, wreg[s], accA, 0, 0, 0); \
    }                                                                          \
    _Pragma("unroll")                                                          \
    for (int s = 7; s < 28; ++s) {                                             \
        half8 a = *(const half8*)(gb + 64 * s + 16 * g);                       \
        half8 b = *(const half8*)(wrow + 32 * s);                              \
        if (s & 1) accB = __builtin_amdgcn_mfma_f32_16x16x32_f16(a, b, accB, 0, 0, 0); \
        else       accA = __builtin_amdgcn_mfma_f32_16x16x32_f16(a, b, accA, 0, 0, 0); \
    }                                                                          \
    f32x4 acc = accA + accB;                                                   \
    if (kh) *(f32x4*)&red[ot][lane] = acc;                                     \
    __syncthreads();                                                           \
    if (!kh) {                                                                 \
        f32x4 p = red[ot][lane];                                               \
        const int o = 16 * ot + lr;                                            \
        _Pragma("unroll")                                                      \
        for (int r = 0; r < 4; ++r)                                            \
            out[((T) * 16 + 4 * g + r) * 64 + o] = acc[r] + p[r];              \
    }                                                                          \
} while (0)

template <int XHALF, int PH>
__global__ __launch_bounds__(512, 4) void kpconv(
    const float* __restrict__ q_pts, const float* __restrict__ s_pts,
    const int*   __restrict__ inds,  const float* __restrict__ x,
    const half_t* __restrict__ xh,   const half_t* __restrict__ sh,
    const half_t* __restrict__ qh,   const half_t* __restrict__ WT,
    float* __restrict__ out)
{
    // LDS: 57856 + 2048 + 8192 + 4096 = 72192 B -> 2 blocks/CU (16 waves/CU)
    __shared__ __align__(16) char    g_mem[16 * GPITCH];          // G[q][i*28+l] fp16
    __shared__ __align__(16) unsigned short idx_lds[2][16][32];   // double-buffered
    __shared__ __align__(16) half4_t nbr_lds[2][16][32];          // double-buffered fp16
    __shared__ __align__(16) f32x4   red[4][64];                  // phase-D K-reduction

    const int tid  = threadIdx.x;
    const int lane = tid & 63, wid = tid >> 6;
    const int lr   = lane & 15, g = lane >> 4;
    const int aq   = tid >> 5,  ah = tid & 31;      // phase-A mapping: 16q x 32h
    const int ot   = wid & 3,   kh = wid >> 2;      // phase-D wave role

    // this lane's two kernel points: l0 = lr (always valid), l1 = lr+16 (>=27 -> w=0)
    const float kx0 = (float)((lr / 3) % 3 - 1) * KP_S;
    const float ky0 = (float)( lr / 9      - 1) * KP_S;
    const float kz0 = (float)( lr % 3      - 1) * KP_S;
    const int   l1  = lr + 16;
    const float kx1 = (float)((l1 / 3) % 3 - 1) * KP_S;
    const float ky1 = (float)( l1 / 9      - 1) * KP_S;
    const float kz1 = (float)( l1 % 3      - 1) * KP_S;
    const float cbias = (l1 < 27) ? 1.f : -1.f;     // forces w1=0 for pad rows

    // loop-invariant phase-D addressing + persistent WT regs (steps 0..6)
    const half_t* wrow = WT + (16 * ot + lr) * 1792 + kh * 896 + 8 * g;
    const char*   gb   = g_mem + lr * GPITCH + kh * 1792;
    half8 wreg[7];
    #pragma unroll
    for (int p = 0; p < 7; ++p) wreg[p] = *(const half8*)(wrow + 32 * p);

    // ---- prologue: phase A for first tile -> buffer 0 (f32 source, once) ----
    {
        int n   = blockIdx.x * 16 + aq;
        int idx = inds[n * 32 + ah];
        idx_lds[0][aq][ah] = (unsigned short)idx;
        float dx = s_pts[idx * 3 + 0] - q_pts[n * 3 + 0];
        float dy = s_pts[idx * 3 + 1] - q_pts[n * 3 + 1];
        float dz = s_pts[idx * 3 + 2] - q_pts[n * 3 + 2];
        H4 nv;
        nv.h2[0] = __builtin_amdgcn_cvt_pkrtz(dx, dy);
        nv.h2[1] = __builtin_amdgcn_cvt_pkrtz(dz, 0.f);
        nbr_lds[0][aq][ah] = nv.v;
    }
    __syncthreads();

    half4_t xv[8];
    ISSUE_XV1(0, 2 * wid, xv);
    const int t1 = (blockIdx.x + NBLK < NTILE) ? blockIdx.x + NBLK : blockIdx.x;
    int idxReg = inds[(t1 * 16 + aq) * 32 + ah];

    int cur = 0;
    for (int t = blockIdx.x; t < NTILE; t += NBLK) {
        const int tn  = (t + NBLK < NTILE) ? t + NBLK : t;          // next (clamped)
        const int tnn = (t + 2 * NBLK < NTILE) ? t + 2 * NBLK : tn; // next-next
        const int nnq = tn * 16 + aq;                               // row for nbr calc
        BODY(t, tnn, cur, xv);
        cur ^= 1;
    }
}

extern "C" void kernel_launch(void* const* d_in, const int* in_sizes, int n_in,
                              void* d_out, int out_size, void* d_ws, size_t ws_size,
                              hipStream_t stream) {
    const float* q_pts = (const float*)d_in[0];
    const float* s_pts = (const float*)d_in[1];
    const int*   inds  = (const int*)d_in[2];
    const float* x     = (const float*)d_in[3];
    const float* W     = (const float*)d_in[4];
    float* out = (float*)d_out;
    half_t* WT = (half_t*)d_ws;                                        // 229376 B
    half_t* xh = (half_t*)((char*)d_ws + WT_BYTES);                    // 5120000 B
    half_t* sh = (half_t*)((char*)d_ws + WT_BYTES + XH_BYTES);         // 320000 B
    half_t* qh = (half_t*)((char*)d_ws + WT_BYTES + XH_BYTES + PH_BYTES); // 320000 B

    build_wt<<<448, 256, 0, stream>>>(W, WT);                          // exact
    const size_t need_xh   = (size_t)WT_BYTES + XH_BYTES;
    const size_t need_full = need_xh + 2 * (size_t)PH_BYTES;
    if (ws_size >= need_full) {
        build_xh<<<2500, 256, 0, stream>>>(x, xh);
        build_ph<<<157, 256, 0, stream>>>(q_pts, s_pts, qh, sh);
        kpconv<1, 1><<<NBLK, 512, 0, stream>>>(q_pts, s_pts, inds, x, xh, sh, qh, WT, out);
    } else if (ws_size >= need_xh) {
        build_xh<<<2500, 256, 0, stream>>>(x, xh);
        kpconv<1, 0><<<NBLK, 512, 0, stream>>>(q_pts, s_pts, inds, x, xh, sh, qh, WT, out);
    } else {
        kpconv<0, 0><<<NBLK, 512, 0, stream>>>(q_pts, s_pts, inds, x, xh, sh, qh, WT, out);
    }
}

// Round 14
// 100.173 us; speedup vs baseline: 1.1997x; 1.1997x over previous
//
#include <hip/hip_runtime.h>

typedef _Float16 half_t;
typedef __fp16   fp16x2 __attribute__((ext_vector_type(2)));
typedef _Float16 half4_t __attribute__((ext_vector_type(4)));
typedef _Float16 half8   __attribute__((ext_vector_type(8)));
typedef float    f32x4   __attribute__((ext_vector_type(4)));
typedef unsigned short u16x8 __attribute__((ext_vector_type(8)));

#define KP_S    0.057735026918962574f  // 0.1/sqrt(3)
#define INV_EXT 11.547005383792515f    // 1/(0.05*sqrt(3))
#define GPITCH  3616                   // G bytes/query: 64*28*2 data + 32 pad
#define NBLK    256                    // persistent blocks = 1/CU (1024 thr, 16 waves)
#define NTILE   2500                   // 40000 queries / 16 per tile
#define WT_BYTES (64 * 1792 * 2)       // 229376
#define XH_BYTES (40000 * 64 * 2)      // 5120000

union H8 { half8 v; fp16x2 h2[4]; };
union H4 { half4_t v; fp16x2 h2[2]; };

// LDS-visibility-only barrier (r12-proven): no vmcnt drain, gathers/out-stores
// stay in flight across it. sched_barrier per rule 18.
#define BAR_LGKM() do {                                                        \
    __asm__ volatile("s_waitcnt lgkmcnt(0)\n\ts_barrier" ::: "memory");        \
    __builtin_amdgcn_sched_barrier(0);                                         \
} while (0)

// WT[o][k], k = i*28 + l (fp16); l==27 zero pad mirrors G's pitch-28 layout.
// Channel permutation c = 4*(i&15) + (i>>4): MFMA column (nt,lr) holds x-channel
// 4*lr+nt so the phase-C gather is one 8B fp16 load per lane per row.
__global__ void build_wt(const float* __restrict__ W, half_t* __restrict__ WT) {
    int t = blockIdx.x * 256 + threadIdx.x;       // 64*1792 = 114688 exact
    if (t >= 64 * 1792) return;
    int o = t / 1792, k = t - o * 1792;
    int i = k / 28,   l = k - i * 28;
    int c = 4 * (i & 15) + (i >> 4);              // permuted channel index
    WT[t] = (l < 27) ? (half_t)W[(l * 64 + c) * 64 + o] : (half_t)0.f;
}

// x (f32, [40000][64]) -> xh (fp16, same layout): 128 B/row = 1 cache line
__global__ void build_xh(const float* __restrict__ x, half_t* __restrict__ xh) {
    int t = blockIdx.x * 256 + threadIdx.x;       // 2500*256 = 640000 exact
    f32x4 v = *(const f32x4*)(x + t * 4);
    H4 h;
    h.h2[0] = __builtin_amdgcn_cvt_pkrtz(v.x, v.y);
    h.h2[1] = __builtin_amdgcn_cvt_pkrtz(v.z, v.w);
    *(half4_t*)(xh + t * 4) = h.v;
}

// issue one query's x-gather into 8 half4 regs (16 VGPR)
#define ISSUE_XV1(BUF, Q, XV) do {                                             \
    u16x8 id8 = *(const u16x8*)&idx_lds[BUF][Q][8 * g];                        \
    _Pragma("unroll")                                                          \
    for (int j = 0; j < 8; ++j) {                                              \
        if constexpr (XHALF) {                                                 \
            XV[j] = *(const half4_t*)(xh + (int)id8[j] * 64 + 4 * lr);         \
        } else {                                                               \
            f32x4 t4 = *(const f32x4*)(x + (int)id8[j] * 64 + 4 * lr);         \
            H4 hh;                                                             \
            hh.h2[0] = __builtin_amdgcn_cvt_pkrtz(t4.x, t4.y);                 \
            hh.h2[1] = __builtin_amdgcn_cvt_pkrtz(t4.z, t4.w);                 \
            XV[j] = hh.v;                                                      \
        }                                                                      \
    }                                                                          \
} while (0)

// transpose 8 half4 -> 4 half8 B-fragments (pure fp16 lane-local moves)
#define PACK_B(XV, BF) do {                                                    \
    _Pragma("unroll")                                                          \
    for (int nt = 0; nt < 4; ++nt) {                                           \
        half8 b;                                                               \
        _Pragma("unroll")                                                      \
        for (int j = 0; j < 8; ++j) b[j] = XV[j][nt];                          \
        BF[nt].v = b;                                                          \
    }                                                                          \
} while (0)

// per-lane influence weights + stage-1 MFMAs + G dump for one query into GBASE
#define MFMA_DUMP(Q, CUR, GBASE, BF) do {                                      \
    float w0v[8], w1v[8];                                                      \
    _Pragma("unroll")                                                          \
    for (int j = 0; j < 8; ++j) {                                              \
        half4_t nb = nbr_lds[CUR][Q][8 * g + j];                               \
        float nx = (float)nb[0], ny = (float)nb[1], nz = (float)nb[2];         \
        float dx = nx - kx0, dy = ny - ky0, dz = nz - kz0;                     \
        w0v[j] = fmaxf(fmaf(__builtin_amdgcn_sqrtf(dx*dx + dy*dy + dz*dz), -INV_EXT, 1.f), 0.f); \
        float ex = nx - kx1, ey = ny - ky1, ez = nz - kz1;                     \
        w1v[j] = fmaxf(fmaf(__builtin_amdgcn_sqrtf(ex*ex + ey*ey + ez*ez), -INV_EXT, cbias), 0.f); \
    }                                                                          \
    H8 A0, A1;                                                                 \
    _Pragma("unroll")                                                          \
    for (int p = 0; p < 4; ++p) {                                              \
        A0.h2[p] = __builtin_amdgcn_cvt_pkrtz(w0v[2*p], w0v[2*p+1]);           \
        A1.h2[p] = __builtin_amdgcn_cvt_pkrtz(w1v[2*p], w1v[2*p+1]);           \
    }                                                                          \
    char* gq = (GBASE) + (Q) * GPITCH;                                         \
    _Pragma("unroll")                                                          \
    for (int nt = 0; nt < 4; ++nt) {                                           \
        f32x4 z = {0.f, 0.f, 0.f, 0.f};                                        \
        f32x4 c0 = __builtin_amdgcn_mfma_f32_16x16x32_f16(A0.v, BF[nt].v, z, 0, 0, 0); \
        f32x4 c1 = __builtin_amdgcn_mfma_f32_16x16x32_f16(A1.v, BF[nt].v, z, 0, 0, 0); \
        const int ic = 16 * nt + lr;                                           \
        H4 h0;                                                                 \
        h0.h2[0] = __builtin_amdgcn_cvt_pkrtz(c0[0], c0[1]);                   \
        h0.h2[1] = __builtin_amdgcn_cvt_pkrtz(c0[2], c0[3]);                   \
        *(half4_t*)(gq + 2 * (ic * 28 + 4 * g)) = h0.v;                        \
        if (4 * g < 12) {                                                      \
            H4 h1;                                                             \
            h1.h2[0] = __builtin_amdgcn_cvt_pkrtz(c1[0], c1[1]);               \
            h1.h2[1] = __builtin_amdgcn_cvt_pkrtz(c1[2], c1[3]);               \
            *(half4_t*)(gq + 2 * (ic * 28 + 16 + 4 * g)) = h1.v;               \
        }                                                                      \
    }                                                                          \
} while (0)

template <int XHALF>
__global__ __launch_bounds__(1024, 4) void kpconv(
    const float* __restrict__ q_pts, const float* __restrict__ s_pts,
    const int*   __restrict__ inds,  const float* __restrict__ x,
    const half_t* __restrict__ xh,   const half_t* __restrict__ WT,
    float* __restrict__ out)
{
    // LDS: 115712 + 2048 + 8192 + 8192 = 134144 B -> 1 block/CU (16 waves/CU)
    __shared__ __align__(16) char    g_mem[2][16 * GPITCH];       // double-buffered G
    __shared__ __align__(16) unsigned short idx_lds[2][16][32];
    __shared__ __align__(16) half4_t nbr_lds[2][16][32];
    __shared__ __align__(16) f32x4   red[2][4][64];               // dbuf K-reduction

    const int tid  = threadIdx.x;
    const int lane = tid & 63, wid = tid >> 6;      // wid 0..15
    const int lr   = lane & 15, g = lane >> 4;
    const bool isP = (wid < 8);                     // producers: waves 0..7
    const int pw   = wid;                           // producer wave id
    const int cw   = wid - 8;                       // consumer wave id 0..7
    const int ot   = cw & 3,  kh = cw >> 2;         // consumer role (4 ot x 2 kh)
    const int aq   = tid >> 5, ah = tid & 31;       // phase-A map (P threads only)
    const int bid  = blockIdx.x;
    const int nt   = (NTILE - bid + NBLK - 1) / NBLK;   // tiles for this block (9 or 10)

    // this lane's two kernel points (producers): l0 = lr, l1 = lr+16 (>=27 -> w=0)
    const float kx0 = (float)((lr / 3) % 3 - 1) * KP_S;
    const float ky0 = (float)( lr / 9      - 1) * KP_S;
    const float kz0 = (float)( lr % 3      - 1) * KP_S;
    const int   l1  = lr + 16;
    const float kx1 = (float)((l1 / 3) % 3 - 1) * KP_S;
    const float ky1 = (float)( l1 / 9      - 1) * KP_S;
    const float kz1 = (float)( l1 % 3      - 1) * KP_S;
    const float cbias = (l1 < 27) ? 1.f : -1.f;

    // consumer loop-invariant addressing
    const half_t* wrow = WT + (16 * ot + lr) * 1792 + kh * 896 + 8 * g;

    // ---- prologue: phase A for T0 -> buffer 0 (producer threads) ----
    if (isP) {
        int n   = bid * 16 + aq;
        int idx = inds[n * 32 + ah];
        idx_lds[0][aq][ah] = (unsigned short)idx;
        float dx = s_pts[idx * 3 + 0] - q_pts[n * 3 + 0];
        float dy = s_pts[idx * 3 + 1] - q_pts[n * 3 + 1];
        float dz = s_pts[idx * 3 + 2] - q_pts[n * 3 + 2];
        H4 nv;
        nv.h2[0] = __builtin_amdgcn_cvt_pkrtz(dx, dy);
        nv.h2[1] = __builtin_amdgcn_cvt_pkrtz(dz, 0.f);
        nbr_lds[0][aq][ah] = nv.v;
    }
    __syncthreads();

    half4_t xv[8];
    int idxReg = 0;
    if (isP) {
        ISSUE_XV1(0, 2 * pw, xv);
        const int t1 = (nt > 1) ? bid + NBLK : bid;
        idxReg = inds[(t1 * 16 + aq) * 32 + ah];
    }

    f32x4 savedAcc = {0.f, 0.f, 0.f, 0.f};
    for (int i = 0; i <= nt; ++i) {
        const int cur = i & 1;
        if (isP) {
            if (i < nt) {
                const int T = bid + i * NBLK;
                // qB gather for current tile (in flight across qA compute)
                half4_t xvB[8];
                ISSUE_XV1(cur, 2 * pw + 1, xvB);
                // idx chain: idxReg holds T_{i+1}; prefetch T_{i+2}
                const int idxN = idxReg;
                const int iNN  = (i + 2 < nt) ? i + 2 : nt - 1;
                idxReg = inds[((bid + iNN * NBLK) * 16 + aq) * 32 + ah];
                // qA stage-1
                H8 BFA[4];
                PACK_B(xv, BFA);
                MFMA_DUMP(2 * pw, cur, g_mem[cur], BFA);
                // nbr chain for T_{i+1}
                const int iN  = (i + 1 < nt) ? i + 1 : nt - 1;
                const int nnq = (bid + iN * NBLK) * 16 + aq;
                float dx = s_pts[idxN * 3 + 0] - q_pts[nnq * 3 + 0];
                float dy = s_pts[idxN * 3 + 1] - q_pts[nnq * 3 + 1];
                float dz = s_pts[idxN * 3 + 2] - q_pts[nnq * 3 + 2];
                H4 nv;
                nv.h2[0] = __builtin_amdgcn_cvt_pkrtz(dx, dy);
                nv.h2[1] = __builtin_amdgcn_cvt_pkrtz(dz, 0.f);
                // qB stage-1
                H8 BFB[4];
                PACK_B(xvB, BFB);
                MFMA_DUMP(2 * pw + 1, cur, g_mem[cur], BFB);
                idx_lds[cur ^ 1][aq][ah] = (unsigned short)idxN;
                nbr_lds[cur ^ 1][aq][ah] = nv.v;
                (void)T;
            }
        } else {
            // deferred epilogue for tile T_{i-2} (red written last iteration)
            if (kh == 0 && i >= 2) {
                const int Tp = bid + (i - 2) * NBLK;
                f32x4 p = red[(i - 1) & 1][ot][lane];
                const int o = 16 * ot + lr;
                #pragma unroll
                for (int r = 0; r < 4; ++r)
                    out[(Tp * 16 + 4 * g + r) * 64 + o] = savedAcc[r] + p[r];
            }
            // K-loop for tile T_{i-1} from G[cur^1]
            if (i >= 1) {
                const char* gb = g_mem[cur ^ 1] + lr * GPITCH + kh * 1792;
                f32x4 accA = {0.f, 0.f, 0.f, 0.f}, accB = {0.f, 0.f, 0.f, 0.f};
                #pragma unroll
                for (int s = 0; s < 28; s += 2) {
                    half8 aA = *(const half8*)(gb + 64 * s + 16 * g);
                    half8 bA = *(const half8*)(wrow + 32 * s);
                    accA = __builtin_amdgcn_mfma_f32_16x16x32_f16(aA, bA, accA, 0, 0, 0);
                    half8 aB = *(const half8*)(gb + 64 * (s + 1) + 16 * g);
                    half8 bB = *(const half8*)(wrow + 32 * (s + 1));
                    accB = __builtin_amdgcn_mfma_f32_16x16x32_f16(aB, bB, accB, 0, 0, 0);
                }
                f32x4 acc = accA + accB;
                if (kh) *(f32x4*)&red[cur][ot][lane] = acc;
                else    savedAcc = acc;
            }
        }
        BAR_LGKM();
        // refill qA gather for T_{i+1} (idx_lds[cur^1] written pre-barrier)
        if (isP && i + 1 < nt) ISSUE_XV1(cur ^ 1, 2 * pw, xv);
    }

    // drain: last tile T_{nt-1} (K-loop ran at i=nt, red[nt&1] written, synced)
    if (!isP && kh == 0) {
        const int Tp = bid + (nt - 1) * NBLK;
        f32x4 p = red[nt & 1][ot][lane];
        const int o = 16 * ot + lr;
        #pragma unroll
        for (int r = 0; r < 4; ++r)
            out[(Tp * 16 + 4 * g + r) * 64 + o] = savedAcc[r] + p[r];
    }
}

extern "C" void kernel_launch(void* const* d_in, const int* in_sizes, int n_in,
                              void* d_out, int out_size, void* d_ws, size_t ws_size,
                              hipStream_t stream) {
    const float* q_pts = (const float*)d_in[0];
    const float* s_pts = (const float*)d_in[1];
    const int*   inds  = (const int*)d_in[2];
    const float* x     = (const float*)d_in[3];
    const float* W     = (const float*)d_in[4];
    float* out = (float*)d_out;
    half_t* WT = (half_t*)d_ws;                               // 229376 B
    half_t* xh = (half_t*)((char*)d_ws + WT_BYTES);           // 5120000 B

    build_wt<<<448, 256, 0, stream>>>(W, WT);                 // 448*256 = 114688 exact
    if (ws_size >= (size_t)(WT_BYTES + XH_BYTES)) {
        build_xh<<<2500, 256, 0, stream>>>(x, xh);
        kpconv<1><<<NBLK, 1024, 0, stream>>>(q_pts, s_pts, inds, x, xh, WT, out);
    } else {
        kpconv<0><<<NBLK, 1024, 0, stream>>>(q_pts, s_pts, inds, x, xh, WT, out);
    }
}